// Round 6
// baseline (310.704 us; speedup 1.0000x reference)
//
#include <hip/hip_runtime.h>
#include <hip/hip_fp16.h>

#define NWORK 16     // worker blocks: one batch each
#define NPACK 192    // weight-pack blocks
#define NBTOT 208
#define NT    1024
#define FPAD  16     // 64 B per flag slot
#define SMEM_BYTES 138240

typedef _Float16 h2_t  __attribute__((ext_vector_type(2)));
typedef _Float16 half8 __attribute__((ext_vector_type(8)));
typedef float    f32x4 __attribute__((ext_vector_type(4)));

#define AG_LD(p)    __hip_atomic_load((p), __ATOMIC_RELAXED, __HIP_MEMORY_SCOPE_AGENT)

// pack two fp32 -> fp16 pair (RNE)
__device__ __forceinline__ unsigned pkh(float a, float b) {
    const __half2 h = __floats2half2_rn(a, b);
    return __builtin_bit_cast(unsigned, h);
}
// fp16-pair dot product with fp32 accumulate (v_dot2_f32_f16) — U2 matvec only
__device__ __forceinline__ float fdot2(unsigned w, unsigned a, float c) {
#if __has_builtin(__builtin_amdgcn_fdot2)
    return __builtin_amdgcn_fdot2(__builtin_bit_cast(h2_t, w),
                                  __builtin_bit_cast(h2_t, a), c, false);
#else
    const float2 fw = __half22float2(__builtin_bit_cast(__half2, w));
    const float2 fa = __half22float2(__builtin_bit_cast(__half2, a));
    return c + fw.x * fa.x + fw.y * fa.y;
#endif
}

__device__ __forceinline__ half8 ldw(const unsigned* p) {
    return __builtin_bit_cast(half8, *(const uint4*)p);
}
__device__ __forceinline__ f32x4 MF(half8 a, half8 b, f32x4 c) {
    return __builtin_amdgcn_mfma_f32_16x16x32_f16(a, b, c, 0, 0, 0);
}

// ---- validated block0-fanout barrier (single use: after weight pack) ----
__device__ __forceinline__ void bar_arrive(int n, unsigned* flags, int bid) {
    __syncthreads();
    if (threadIdx.x == 0)
        __hip_atomic_store(&flags[bid * FPAD], (unsigned)n, __ATOMIC_RELEASE,
                           __HIP_MEMORY_SCOPE_AGENT);
}
__device__ __forceinline__ void bar_wait(int n, unsigned* flags, unsigned* rel,
                                         int bid, bool fence) {
    if (bid == 0) {
        if (threadIdx.x < NBTOT) {
            while ((int)__hip_atomic_load(&flags[threadIdx.x * FPAD],
                                          __ATOMIC_RELAXED,
                                          __HIP_MEMORY_SCOPE_AGENT) < n)
                __builtin_amdgcn_s_sleep(1);
        }
        __syncthreads();
        if (threadIdx.x < 16)
            __hip_atomic_store(&rel[(n * 16 + threadIdx.x) * FPAD], (unsigned)n,
                               __ATOMIC_RELEASE, __HIP_MEMORY_SCOPE_AGENT);
    } else {
        if (threadIdx.x == 0) {
            while ((int)__hip_atomic_load(&rel[(n * 16 + (bid & 15)) * FPAD],
                                          __ATOMIC_RELAXED,
                                          __HIP_MEMORY_SCOPE_AGENT) < n)
                __builtin_amdgcn_s_sleep(1);
        }
    }
    if (fence) __builtin_amdgcn_fence(__ATOMIC_ACQUIRE, "agent");
    __syncthreads();
}

// MFMA-pack (matrices 0..8): uint idx = (t*8+kc)*256 + (g*16+lc)*4 + sl —
// lane l = g*16+lc holds col t*16+lc, k = kc*32 + g*8 + {0..7}. Identical k-map
// to the A-staging read (validated R5) -> internal k relabeling cancels.
// Old pack (matrices 9..11, U2 fdot2 path): idx = (k>>3)*1024 + c*4 + ((k>>1)&3).

__global__ __launch_bounds__(NT)
__attribute__((amdgpu_waves_per_eu(4, 4)))
void fused_k(
    const float* __restrict__ feat,   // [16][128][256]
    const float* __restrict__ mask,   // [16][128]
    const float* __restrict__ aggW,   // [3][256][256]
    const float* __restrict__ aggB,   // [3][256]
    const float* __restrict__ attnW,  // [3][256][512]
    const float* __restrict__ updW,   // [3][256][512]
    const float* __restrict__ updB,   // [3][256]
    unsigned* __restrict__ WtH,       // 12 * 32768 uints (fp16-pair packed)
    unsigned* flags, unsigned* rel,
    float* __restrict__ out)
{
    // Dynamic LDS map (floats / uint slots):
    //   xbuf  [0,16896)        : x  A-layout, 128 rows x 132 uints
    //   hidb  [16896,33792)    : hid A-layout (overlay below lives in its
    //                            dead window between A-frag load & hid' write)
    //     pm/pd/pn [16896+{0,2048,4096}) : per-rowtile softmax partials [8][256]
    //     s2m/s2d/s2n [23040+{0,1024,2048}) : stage-1 combine [4][256]
    //   aggl32 [33792,34048)   aggh(u) [34048,34176)
    //   accl  [34176,34432)    msk [34432,34560)
    extern __shared__ float lds[];
    unsigned* xbuf   = (unsigned*)lds;
    unsigned* hidb   = (unsigned*)lds + 16896;
    float*    pm     = lds + 16896;
    float*    pd     = lds + 18944;
    float*    pn     = lds + 20992;
    float*    s2m    = lds + 23040;
    float*    s2d    = lds + 24064;
    float*    s2n    = lds + 25088;
    float*    aggl32 = lds + 33792;
    unsigned* aggh   = (unsigned*)lds + 34048;
    float*    accl   = lds + 34176;
    float*    msk    = lds + 34432;

    const int bid = blockIdx.x;
    const int tid = threadIdx.x;

    // ================= pack blocks: transpose + fp16-pack 12 mats, then exit
    if (bid >= NWORK) {
        float (*Tl)[65] = (float (*)[65])lds;
        const int bb = bid - NWORK;
        const int m = bb >> 4, t = bb & 15, tr = t >> 2, tc = t & 3;
        const float* src; int stride, off;
        if (m < 3)      { src = aggW  + (size_t)m * 65536;        stride = 256; off = 0;   }
        else if (m < 6) { src = attnW + (size_t)(m - 3) * 131072; stride = 512; off = 0;   }
        else if (m < 9) { src = updW  + (size_t)(m - 6) * 131072; stride = 512; off = 0;   }
        else            { src = updW  + (size_t)(m - 9) * 131072; stride = 512; off = 256; }
        unsigned* dstu = WtH + (size_t)m * 32768;
        {
            const int row = tid >> 4, q = (tid & 15) * 4;
            const float4 v = *(const float4*)(src + (size_t)(tr * 64 + row) * stride + off + tc * 64 + q);
            Tl[row][q + 0] = v.x; Tl[row][q + 1] = v.y;
            Tl[row][q + 2] = v.z; Tl[row][q + 3] = v.w;
        }
        __syncthreads();
        #pragma unroll
        for (int it = 0; it < 2; ++it) {
            const int j = it * NT + tid, cl = j >> 5, pr = j & 31;
            const unsigned val = pkh(Tl[cl][pr * 2], Tl[cl][pr * 2 + 1]);
            const int C = tr * 64 + cl, P = tc * 32 + pr;
            size_t idx;
            if (m < 9) {
                const int tt = C >> 4, lc = C & 15;
                const int kc = P >> 4, g = (P >> 2) & 3, sl = P & 3;
                idx = (size_t)((tt * 8 + kc) * 256 + (g * 16 + lc) * 4 + sl);
            } else {
                idx = (size_t)(P >> 2) * 1024 + (size_t)C * 4 + (P & 3);
            }
            dstu[idx] = val;
        }
        bar_arrive(1, flags, bid);
        return;
    }

    // ================= worker blocks: one batch each, fully block-local loop
    const int b = bid;

    // P0a: hid0 = fp16(feat*mask) into A-layout (row stride 132 uints)
    {
        const float* fb = feat + (size_t)b * 128 * 256;
        #pragma unroll
        for (int it = 0; it < 8; ++it) {
            const int j = it * NT + tid, r = j >> 6, pp = (j & 63) * 2;
            const float4 f = *(const float4*)(fb + (size_t)r * 256 + pp * 2);
            const float mv = mask[b * 128 + r];
            hidb[r * 132 + pp]     = pkh(f.x * mv, f.y * mv);
            hidb[r * 132 + pp + 1] = pkh(f.z * mv, f.w * mv);
        }
        if (tid < 128) msk[tid] = mask[b * 128 + tid];
    }

    bar_arrive(1, flags, bid);
    bar_wait(1, flags, rel, bid, true);   // acquire packed weights

    const int wv = tid >> 6, lane = tid & 63;
    const int rt = wv & 7, ch = wv >> 3;          // row-tile 0..7, col-half 0..1
    const int lr = lane & 15, lg = lane >> 4;
    const int arow = (rt * 16 + lr) * 132 + lg * 4;   // A-frag base (uints)

    for (int i = 0; i < 3; ++i) {
        // ---- x = hid @ aggW^T + aggB (per wave: its row-tile x 8 col-tiles)
        half8 a[8];
        #pragma unroll
        for (int kc = 0; kc < 8; ++kc) a[kc] = ldw(hidb + arow + kc * 16);
        const unsigned* W0 = WtH + (size_t)i * 32768;
        f32x4 xd[8];
        #pragma unroll
        for (int j = 0; j < 8; ++j) {
            const int ct = ch * 8 + j;
            f32x4 acc = {};
            #pragma unroll
            for (int kc = 0; kc < 8; ++kc)
                acc = MF(a[kc], ldw(W0 + (size_t)(ct * 8 + kc) * 256 + lane * 4), acc);
            const float bbv = aggB[i * 256 + ct * 16 + lr];
            #pragma unroll
            for (int q = 0; q < 4; ++q) acc[q] += bbv;
            xd[j] = acc;
            float pv[4];
            #pragma unroll
            for (int q = 0; q < 4; ++q) pv[q] = __shfl_xor(acc[q], 1);
            if (!(lr & 1)) {
                #pragma unroll
                for (int q = 0; q < 4; ++q)
                    xbuf[(rt * 16 + lg * 4 + q) * 132 + ct * 8 + (lr >> 1)] = pkh(acc[q], pv[q]);
            }
        }
        __syncthreads();

        // ---- p = x @ W1^T -> per-(rowtile, channel) online partials into LDS
        #pragma unroll
        for (int kc = 0; kc < 8; ++kc) a[kc] = ldw(xbuf + arow + kc * 16);
        const unsigned* W1 = WtH + (size_t)(3 + i) * 32768;
        #pragma unroll
        for (int j = 0; j < 8; ++j) {
            const int ct = ch * 8 + j;
            f32x4 acc = {};
            #pragma unroll
            for (int kc = 0; kc < 8; ++kc)
                acc = MF(a[kc], ldw(W1 + (size_t)(ct * 8 + kc) * 256 + lane * 4), acc);
            float mm = fmaxf(fmaxf(acc[0], acc[1]), fmaxf(acc[2], acc[3]));
            mm = fmaxf(mm, __shfl_xor(mm, 16));
            mm = fmaxf(mm, __shfl_xor(mm, 32));
            float dd = 0.f, nv = 0.f;
            #pragma unroll
            for (int q = 0; q < 4; ++q) {
                const float e = __expf(acc[q] - mm);
                dd += e;
                nv += e * xd[j][q];
            }
            dd += __shfl_xor(dd, 16); dd += __shfl_xor(dd, 32);
            nv += __shfl_xor(nv, 16); nv += __shfl_xor(nv, 32);
            if (lg == 0) {
                const int cc = ct * 16 + lr;
                pm[rt * 256 + cc] = mm;
                pd[rt * 256 + cc] = dd;
                pn[rt * 256 + cc] = nv;
            }
        }

        // ---- xU1 = x @ U1^T (independent of combine; overlaps partial latency)
        const unsigned* U1 = WtH + (size_t)(6 + i) * 32768;
        f32x4 xu[8];
        #pragma unroll
        for (int j = 0; j < 8; ++j) {
            const int ct = ch * 8 + j;
            f32x4 acc = {};
            #pragma unroll
            for (int kc = 0; kc < 8; ++kc)
                acc = MF(a[kc], ldw(U1 + (size_t)(ct * 8 + kc) * 256 + lane * 4), acc);
            xu[j] = acc;
        }
        __syncthreads();   // partials visible

        // ---- combine stage 1: 4 groups x 256 channels (rt pairs)
        {
            const int h = tid >> 8, cix = tid & 255;
            const float m0 = pm[(2 * h) * 256 + cix], m1 = pm[(2 * h + 1) * 256 + cix];
            const float Mx = fmaxf(m0, m1);
            const float e0 = __expf(m0 - Mx), e1 = __expf(m1 - Mx);
            s2m[h * 256 + cix] = Mx;
            s2d[h * 256 + cix] = pd[(2 * h) * 256 + cix] * e0 + pd[(2 * h + 1) * 256 + cix] * e1;
            s2n[h * 256 + cix] = pn[(2 * h) * 256 + cix] * e0 + pn[(2 * h + 1) * 256 + cix] * e1;
        }
        __syncthreads();
        // ---- combine stage 2 + sigmoid
        if (tid < 256) {
            float M = s2m[tid], D = s2d[tid], Nv = s2n[tid];
            #pragma unroll
            for (int h = 1; h < 4; ++h) {
                const float mh = s2m[h * 256 + tid];
                const float Mx = fmaxf(M, mh);
                const float ea = __expf(M - Mx), eb = __expf(mh - Mx);
                D  = D * ea + s2d[h * 256 + tid] * eb;
                Nv = Nv * ea + s2n[h * 256 + tid] * eb;
                M = Mx;
            }
            aggl32[tid] = 1.f / (1.f + __expf(-(Nv / D)));
        }
        __syncthreads();
        if (tid < 128) aggh[tid] = pkh(aggl32[2 * tid], aggl32[2 * tid + 1]);
        __syncthreads();

        // ---- U2 matvec (once per batch), 4-way k-split over thread quarters
        {
            const unsigned* Uq = WtH + (size_t)(9 + i) * 32768;
            const int qq = tid >> 8, c = tid & 255, g0 = qq * 8;
            float au = 0.f;
            #pragma unroll
            for (int jx = 0; jx < 8; ++jx) {
                const uint4 w  = *(const uint4*)(Uq + (size_t)(g0 + jx) * 1024 + c * 4);
                const uint4 av = *(const uint4*)&aggh[(g0 + jx) * 4];
                au = fdot2(w.x, av.x, au);
                au = fdot2(w.y, av.y, au);
                au = fdot2(w.z, av.z, au);
                au = fdot2(w.w, av.w, au);
            }
            s2m[qq * 256 + c] = au;   // reuse stage-1 plane (dead now)
        }
        __syncthreads();
        if (tid < 256)
            accl[tid] = s2m[tid] + s2m[256 + tid] + s2m[512 + tid] + s2m[768 + tid]
                      + updB[i * 256 + tid];
        __syncthreads();

        // ---- epilogue: hid' = (xU1 + accU) * mask  (or final out, unmasked)
        if (i < 2) {
            #pragma unroll
            for (int j = 0; j < 8; ++j) {
                const int ct = ch * 8 + j;
                const float av = accl[ct * 16 + lr];
                float hv[4], pv[4];
                #pragma unroll
                for (int q = 0; q < 4; ++q)
                    hv[q] = (xu[j][q] + av) * msk[rt * 16 + lg * 4 + q];
                #pragma unroll
                for (int q = 0; q < 4; ++q) pv[q] = __shfl_xor(hv[q], 1);
                if (!(lr & 1)) {
                    #pragma unroll
                    for (int q = 0; q < 4; ++q)
                        hidb[(rt * 16 + lg * 4 + q) * 132 + ct * 8 + (lr >> 1)] = pkh(hv[q], pv[q]);
                }
            }
            __syncthreads();
        } else {
            float* ob = out + (size_t)b * 128 * 256;
            #pragma unroll
            for (int j = 0; j < 8; ++j) {
                const int ct = ch * 8 + j;
                const float av = accl[ct * 16 + lr];
                #pragma unroll
                for (int q = 0; q < 4; ++q)
                    ob[(size_t)(rt * 16 + lg * 4 + q) * 256 + ct * 16 + lr] = xu[j][q] + av;
            }
        }
    }
}

extern "C" void kernel_launch(void* const* d_in, const int* in_sizes, int n_in,
                              void* d_out, int out_size, void* d_ws, size_t ws_size,
                              hipStream_t stream) {
    const float* feat  = (const float*)d_in[0];
    const float* mask  = (const float*)d_in[1];
    const float* aggW  = (const float*)d_in[2];
    const float* aggB  = (const float*)d_in[3];
    const float* attnW = (const float*)d_in[4];
    // d_in[5] = attnB: cancels in softmax (constant along the s axis)
    const float* updW  = (const float*)d_in[6];
    const float* updB  = (const float*)d_in[7];

    unsigned* WtH   = (unsigned*)d_ws;                 // 12 * 32768 uints
    unsigned* flags = WtH + 12 * 32768;
    unsigned* rel   = flags + 256 * FPAD;

    static bool smem_ok = false;
    if (!smem_ok) {
        hipFuncSetAttribute(reinterpret_cast<const void*>(fused_k),
                            hipFuncAttributeMaxDynamicSharedMemorySize, SMEM_BYTES);
        smem_ok = true;
    }

    fused_k<<<NBTOT, NT, SMEM_BYTES, stream>>>(
        feat, mask, aggW, aggB, attnW, updW, updB,
        WtH, flags, rel, (float*)d_out);
}

// Round 7
// 132.549 us; speedup vs baseline: 2.3441x; 2.3441x over previous
//
#include <hip/hip_runtime.h>
#include <hip/hip_fp16.h>

#define NBLK 256
#define NT   512
#define FPAD 16   // 64 B per flag slot

typedef _Float16 h2_t  __attribute__((ext_vector_type(2)));
typedef _Float16 half8 __attribute__((ext_vector_type(8)));
typedef float    f32x4 __attribute__((ext_vector_type(4)));

#define AG_LD(p)    __hip_atomic_load((p), __ATOMIC_RELAXED, __HIP_MEMORY_SCOPE_AGENT)
#define AG_ST(p, v) __hip_atomic_store((p), (v), __ATOMIC_RELAXED, __HIP_MEMORY_SCOPE_AGENT)

// pack two fp32 -> fp16 pair (RNE)
__device__ __forceinline__ unsigned pkh(float a, float b) {
    const __half2 h = __floats2half2_rn(a, b);
    return __builtin_bit_cast(unsigned, h);
}
// fp16-pair dot product with fp32 accumulate (v_dot2_f32_f16) — U2 matvec only
__device__ __forceinline__ float fdot2(unsigned w, unsigned a, float c) {
#if __has_builtin(__builtin_amdgcn_fdot2)
    return __builtin_amdgcn_fdot2(__builtin_bit_cast(h2_t, w),
                                  __builtin_bit_cast(h2_t, a), c, false);
#else
    const float2 fw = __half22float2(__builtin_bit_cast(__half2, w));
    const float2 fa = __half22float2(__builtin_bit_cast(__half2, a));
    return c + fw.x * fa.x + fw.y * fa.y;
#endif
}

__device__ __forceinline__ half8 ldw(const unsigned* p) {
    return __builtin_bit_cast(half8, *(const uint4*)p);
}
__device__ __forceinline__ f32x4 MF(half8 a, half8 b, f32x4 c) {
    return __builtin_amdgcn_mfma_f32_16x16x32_f16(a, b, c, 0, 0, 0);
}

// ---- arrive: validated release-store of iteration number (logical slot) ----
__device__ __forceinline__ void bar_arrive(int n, unsigned* flags, int lid) {
    __syncthreads();
    if (threadIdx.x == 0)
        __hip_atomic_store(&flags[lid * FPAD], (unsigned)n, __ATOMIC_RELEASE,
                           __HIP_MEMORY_SCOPE_AGENT);
}
// ---- global wait (pack barrier only): R0-validated block0-fanout ----
__device__ __forceinline__ void bar_wait_global(int n, unsigned* flags, unsigned* rel,
                                                int bid, bool fence) {
    if (bid == 0) {
        if (threadIdx.x < NBLK) {
            while ((int)__hip_atomic_load(&flags[threadIdx.x * FPAD],
                                          __ATOMIC_RELAXED,
                                          __HIP_MEMORY_SCOPE_AGENT) < n)
                __builtin_amdgcn_s_sleep(1);
        }
        __syncthreads();
        if (threadIdx.x < 16)
            __hip_atomic_store(&rel[(n * 16 + threadIdx.x) * FPAD], (unsigned)n,
                               __ATOMIC_RELEASE, __HIP_MEMORY_SCOPE_AGENT);
    } else {
        if (threadIdx.x == 0) {
            while ((int)__hip_atomic_load(&rel[(n * 16 + (bid & 15)) * FPAD],
                                          __ATOMIC_RELAXED,
                                          __HIP_MEMORY_SCOPE_AGENT) < n)
                __builtin_amdgcn_s_sleep(1);
        }
    }
    if (fence) __builtin_amdgcn_fence(__ATOMIC_ACQUIRE, "agent");
    __syncthreads();
}
// ---- per-batch wait: threads 0..15 run block0's validated poll over the
// batch's 16 logical flag lines (fan-in 16, single hop, no release RT) ----
__device__ __forceinline__ void bar_wait_batch(int n, unsigned* flags, int b) {
    if (threadIdx.x < 16) {
        while ((int)__hip_atomic_load(&flags[(b * 16 + threadIdx.x) * FPAD],
                                      __ATOMIC_RELAXED,
                                      __HIP_MEMORY_SCOPE_AGENT) < n)
            __builtin_amdgcn_s_sleep(1);
    }
    __syncthreads();
}

// MFMA-pack (matrices 0..8): uint idx = (t*8+kc)*256 + (g*16+lc)*4 + sl —
// lane l = g*16+lc holds col t*16+lc, k = kc*32 + g*8 + {0..7}. Identical k-map
// to the A-staging read (validated R5) -> internal k relabeling cancels.
// Old pack (matrices 9..11, U2 fdot2 path): idx = (k>>3)*1024 + c*4 + ((k>>1)&3).

// Per-batch softmax combine (hoisted tree) + sigmoid + U2 matvec + updB.
__device__ __forceinline__ float phaseB(int i, int b, int c, int rq, int tid,
                                        const float* __restrict__ part,
                                        const unsigned* __restrict__ WtH,
                                        const float* __restrict__ updB,
                                        float* S, float* aggl32, unsigned* aggh) {
    const float* pbase = part + (size_t)((i & 1) * 256 + b * 16 + rq * 8) * 768;
    float m[8], d[8], nn[8];
    #pragma unroll
    for (int j = 0; j < 8; ++j) {                 // 24 loads all in flight
        const float* pp = pbase + (size_t)j * 768;
        m[j]  = AG_LD(pp + c);
        d[j]  = AG_LD(pp + 256 + c);
        nn[j] = AG_LD(pp + 512 + c);
    }
    #pragma unroll
    for (int st = 1; st < 8; st <<= 1) {          // tree combine 8 -> 1
        #pragma unroll
        for (int j = 0; j < 8; j += 2 * st) {
            const float Mn = fmaxf(m[j], m[j + st]);
            const float sa = __expf(m[j] - Mn), sb = __expf(m[j + st] - Mn);
            d[j]  = d[j] * sa + d[j + st] * sb;
            nn[j] = nn[j] * sa + nn[j + st] * sb;
            m[j]  = Mn;
        }
    }
    S[rq * 256 + c] = m[0];
    S[512 + rq * 256 + c] = d[0];
    S[1024 + rq * 256 + c] = nn[0];
    __syncthreads();
    if (rq == 0) {
        const float m0 = S[c], m1 = S[256 + c];
        const float Mx = fmaxf(m0, m1);
        const float s0 = __expf(m0 - Mx), s1 = __expf(m1 - Mx);
        const float dd = S[512 + c] * s0 + S[768 + c] * s1;
        const float nv = S[1024 + c] * s0 + S[1280 + c] * s1;
        aggl32[c] = 1.f / (1.f + __expf(-(nv / dd)));
    }
    __syncthreads();
    if (tid < 128) aggh[tid] = pkh(aggl32[2 * tid], aggl32[2 * tid + 1]);
    __syncthreads();
    // U2 matvec: OLD fp16 layout, k-split across rq halves
    const unsigned* Uq = WtH + (size_t)(9 + i) * 32768;
    const int g0 = rq * 16;
    uint4 buf[8];
    #pragma unroll
    for (int j = 0; j < 8; ++j)
        buf[j] = *(const uint4*)(Uq + (size_t)(g0 + j) * 1024 + c * 4);
    float au = 0.f;
    #pragma unroll
    for (int ph = 0; ph < 2; ++ph) {
        #pragma unroll
        for (int j = 0; j < 8; ++j) {
            const uint4 w = buf[j];
            if (ph < 1)
                buf[j] = *(const uint4*)(Uq + (size_t)(g0 + 8 + j) * 1024 + c * 4);
            const uint4 a = *(const uint4*)&aggh[(g0 + ph * 8 + j) * 4];
            au = fdot2(w.x, a.x, au);
            au = fdot2(w.y, a.y, au);
            au = fdot2(w.z, a.z, au);
            au = fdot2(w.w, a.w, au);
        }
    }
    __syncthreads();
    S[rq * 256 + c] = au;
    __syncthreads();
    return S[c] + S[256 + c] + updB[i * 256 + c];
}

__global__ __launch_bounds__(NT, 2) void fused_k(
    const float* __restrict__ feat,   // [16][128][256]
    const float* __restrict__ mask,   // [16][128]
    const float* __restrict__ aggW,   // [3][256][256]
    const float* __restrict__ aggB,   // [3][256]
    const float* __restrict__ attnW,  // [3][256][512]
    const float* __restrict__ updW,   // [3][256][512]
    const float* __restrict__ updB,   // [3][256]
    unsigned* __restrict__ WtH,       // 12 * 32768 uints (fp16-pair packed)
    float* __restrict__ part,         // 2 * 256 * 768
    unsigned* flags, unsigned* rel,
    float* __restrict__ out)
{
    // A-operand staging: [16 rows][132 uints] (128 k-pair uints + 16B pad),
    // rows 8-15 = zero pad. uint(r, k-pair p2) = r*132 + p2, p2 in [0,128).
    // A-frag read: lane l, chunk kc: ds_read_b128 at r=(l&15), + kc*16+(l>>4)*4
    // -> k = kc*32 + (l>>4)*8 + {0..7}.  132 mod 32 = 4 -> 2-way banks (free).
    __shared__ __align__(16) float ldsf[6408];
    unsigned* hid_uu = (unsigned*)ldsf;            // [0,2112)
    unsigned* x_uu   = (unsigned*)ldsf + 2112;     // [2112,4224)
    float*    accl   = ldsf + 4224;                // [4224,4480)
    float*    S      = ldsf + 4480;                // [4480,6016)
    float*    aggl32 = ldsf + 6016;                // [6016,6272)
    unsigned* aggh   = (unsigned*)ldsf + 6272;     // [6272,6400)
    float*    msk    = ldsf + 6400;                // [6400,6408) (outside Tl overlay)

    const int bid = blockIdx.x;
    const int tid = threadIdx.x;
    const int c   = tid & 255;
    const int rq  = tid >> 8;                 // 0..1 (phaseB k-split)
    const int wid = tid >> 6, lane = tid & 63;
    const int lr  = lane & 15, lg = lane >> 4;
    // XCD co-location: all 16 blocks of a batch share bid%8 (one XCD under the
    // round-robin heuristic). Logical ids: batch b, row-group jj, lid = b*16+jj.
    const int b   = 2 * (bid & 7) + ((bid >> 3) & 1);
    const int jj  = bid >> 4;
    const int lid = b * 16 + jj;
    const int row0 = b * 128 + jj * 8;

    // ---- P0a: stage hid0 = fp16(feat*mask) into A-layout; zero pad rows
    #pragma unroll
    for (int it = 0; it < 2; ++it) {
        const int j = it * 512 + tid, r = j >> 7, pr = j & 127;
        const float2 f = *(const float2*)(feat + (size_t)(row0 + r) * 256 + pr * 2);
        const float mv = mask[row0 + r];
        hid_uu[r * 132 + pr] = pkh(f.x * mv, f.y * mv);
    }
    for (int z = tid; z < 1056; z += NT) hid_uu[1056 + z] = 0u;
    if (tid < 8) msk[tid] = mask[row0 + tid];

    // ---- P0b: transpose + fp16-pack 12 weight mats (blocks 0..191)
    if (bid < 192) {
        float (*Tl)[65] = (float (*)[65])(ldsf + 2112);   // overlay, dead regions
        const int m = bid >> 4, t = bid & 15, tr = t >> 2, tc = t & 3;
        const float* src; int stride, off;
        if (m < 3)      { src = aggW  + (size_t)m * 65536;        stride = 256; off = 0;   }
        else if (m < 6) { src = attnW + (size_t)(m - 3) * 131072; stride = 512; off = 0;   }
        else if (m < 9) { src = updW  + (size_t)(m - 6) * 131072; stride = 512; off = 0;   }
        else            { src = updW  + (size_t)(m - 9) * 131072; stride = 512; off = 256; }
        unsigned* dstu = WtH + (size_t)m * 32768;
        #pragma unroll
        for (int it = 0; it < 2; ++it) {
            const int j = it * 512 + tid, row = j >> 4, q = (j & 15) * 4;
            const float4 v = *(const float4*)(src + (size_t)(tr * 64 + row) * stride + off + tc * 64 + q);
            Tl[row][q + 0] = v.x; Tl[row][q + 1] = v.y;
            Tl[row][q + 2] = v.z; Tl[row][q + 3] = v.w;
        }
        __syncthreads();
        #pragma unroll
        for (int it = 0; it < 4; ++it) {
            const int j = it * 512 + tid, cl = j >> 5, pr = j & 31;
            const unsigned val = pkh(Tl[cl][pr * 2], Tl[cl][pr * 2 + 1]);
            const int C = tr * 64 + cl, P = tc * 32 + pr;
            size_t idx;
            if (m < 9) {   // MFMA B-fragment pack
                const int tt = C >> 4, lc = C & 15;
                const int kc = P >> 4, g = (P >> 2) & 3, sl = P & 3;
                idx = (size_t)((tt * 8 + kc) * 256 + (g * 16 + lc) * 4 + sl);
            } else {       // old pack (U2 fdot2 path)
                idx = (size_t)(P >> 2) * 1024 + (size_t)C * 4 + (P & 3);
            }
            dstu[idx] = val;
        }
    }
    bar_arrive(1, flags, lid);
    bar_wait_global(1, flags, rel, bid, true);   // only fenced barrier

    for (int z = tid; z < 1056; z += NT) x_uu[1056 + z] = 0u;   // pad rows (once)

    f32x4 xu0 = {}, xu1 = {};   // U1 results (D-layout), persist across barrier

    for (int i = 0; i < 3; ++i) {
        if (i > 0) {
            const float accU = phaseB(i - 1, b, c, rq, tid, part, WtH, updB,
                                      S, aggl32, aggh);
            if (rq == 0) accl[c] = accU;
            __syncthreads();
            // hid' = (xU1 + accU) * mask, staged from D-layout into A-layout
            #pragma unroll
            for (int tt = 0; tt < 2; ++tt) {
                const int t = wid * 2 + tt;
                const f32x4 xa = tt ? xu1 : xu0;
                const float av = accl[t * 16 + lr];
                float hv[4], pv[4];
                #pragma unroll
                for (int q = 0; q < 4; ++q)
                    hv[q] = (xa[q] + av) * msk[(lg & 1) * 4 + q];
                #pragma unroll
                for (int q = 0; q < 4; ++q) pv[q] = __shfl_xor(hv[q], 1);
                if (lg < 2 && !(lr & 1)) {
                    const int p2 = t * 8 + (lr >> 1);
                    #pragma unroll
                    for (int q = 0; q < 4; ++q)
                        hid_uu[(lg * 4 + q) * 132 + p2] = pkh(hv[q], pv[q]);
                }
            }
            __syncthreads();
        }

        f32x4 xr0, xr1;   // x (D-layout, biased) for n8

        // ---- P1: x = hid @ aggW^T + aggB via MFMA (B streamed L2->VGPR)
        {
            const unsigned* W0 = WtH + (size_t)i * 32768;
            half8 a[8];
            #pragma unroll
            for (int kc = 0; kc < 8; ++kc)
                a[kc] = ldw(hid_uu + lr * 132 + kc * 16 + lg * 4);
            #pragma unroll
            for (int tt = 0; tt < 2; ++tt) {
                const int t = wid * 2 + tt;
                f32x4 acc = {};
                #pragma unroll
                for (int kc = 0; kc < 8; ++kc)
                    acc = MF(a[kc], ldw(W0 + (size_t)(t * 8 + kc) * 256 + lane * 4), acc);
                const float bb = aggB[i * 256 + t * 16 + lr];
                #pragma unroll
                for (int q = 0; q < 4; ++q) acc[q] += bb;
                if (tt) xr1 = acc; else xr0 = acc;
                float pv[4];
                #pragma unroll
                for (int q = 0; q < 4; ++q) pv[q] = __shfl_xor(acc[q], 1);
                if (lg < 2 && !(lr & 1)) {
                    const int p2 = t * 8 + (lr >> 1);
                    #pragma unroll
                    for (int q = 0; q < 4; ++q)
                        x_uu[(lg * 4 + q) * 132 + p2] = pkh(acc[q], pv[q]);
                }
            }
            __syncthreads();
        }

        // ---- P2: W1 -> softmax partials -> arrive; U1 (hides barrier); wait
        {
            const unsigned* W1 = WtH + (size_t)(3 + i) * 32768;
            const unsigned* U1 = WtH + (size_t)(6 + i) * 32768;
            half8 a2[8];
            #pragma unroll
            for (int kc = 0; kc < 8; ++kc)
                a2[kc] = ldw(x_uu + lr * 132 + kc * 16 + lg * 4);
            float* pb = part + (size_t)((i & 1) * 256 + lid) * 768;
            #pragma unroll
            for (int tt = 0; tt < 2; ++tt) {
                const int t = wid * 2 + tt;
                f32x4 acc = {};
                #pragma unroll
                for (int kc = 0; kc < 8; ++kc)
                    acc = MF(a2[kc], ldw(W1 + (size_t)(t * 8 + kc) * 256 + lane * 4), acc);
                // per-col partials: rows 0-3 in lg==0 lanes, rows 4-7 in lg==1
                const f32x4 xa = tt ? xr1 : xr0;
                float m4 = fmaxf(fmaxf(acc[0], acc[1]), fmaxf(acc[2], acc[3]));
                const float m8 = fmaxf(m4, __shfl_xor(m4, 16));
                float d4 = 0.f, n4 = 0.f;
                #pragma unroll
                for (int q = 0; q < 4; ++q) {
                    const float e = __expf(acc[q] - m8);
                    d4 += e;
                    n4 += e * xa[q];
                }
                const float d8 = d4 + __shfl_xor(d4, 16);
                const float n8 = n4 + __shfl_xor(n4, 16);
                if (lg == 0) {
                    const int cc = t * 16 + lr;
                    AG_ST(pb + cc, m8);
                    AG_ST(pb + 256 + cc, d8);
                    AG_ST(pb + 512 + cc, n8);
                }
            }
            bar_arrive(i + 2, flags, lid);
            #pragma unroll
            for (int tt = 0; tt < 2; ++tt) {
                const int t = wid * 2 + tt;
                f32x4 acc = {};
                #pragma unroll
                for (int kc = 0; kc < 8; ++kc)
                    acc = MF(a2[kc], ldw(U1 + (size_t)(t * 8 + kc) * 256 + lane * 4), acc);
                if (tt) xu1 = acc; else xu0 = acc;
            }
            bar_wait_batch(i + 2, flags, b);   // fan-in 16, single hop, no fence
        }
    }

    // ---- final combine + epilogue: out = xU1 + accU
    {
        const float accU = phaseB(2, b, c, rq, tid, part, WtH, updB, S, aggl32, aggh);
        if (rq == 0) accl[c] = accU;
        __syncthreads();
        #pragma unroll
        for (int tt = 0; tt < 2; ++tt) {
            const int t = wid * 2 + tt;
            const f32x4 xa = tt ? xu1 : xu0;
            const float av = accl[t * 16 + lr];
            if (lg < 2) {
                #pragma unroll
                for (int q = 0; q < 4; ++q)
                    out[(size_t)(row0 + lg * 4 + q) * 256 + t * 16 + lr] = xa[q] + av;
            }
        }
    }
}

extern "C" void kernel_launch(void* const* d_in, const int* in_sizes, int n_in,
                              void* d_out, int out_size, void* d_ws, size_t ws_size,
                              hipStream_t stream) {
    const float* feat  = (const float*)d_in[0];
    const float* mask  = (const float*)d_in[1];
    const float* aggW  = (const float*)d_in[2];
    const float* aggB  = (const float*)d_in[3];
    const float* attnW = (const float*)d_in[4];
    // d_in[5] = attnB: cancels in softmax (constant along the s axis)
    const float* updW  = (const float*)d_in[6];
    const float* updB  = (const float*)d_in[7];

    unsigned* WtH = (unsigned*)d_ws;                   // 12 * 32768 uints
    float* part = (float*)(WtH + 12 * 32768);          // 2 * 256 * 768 floats
    unsigned* flags = (unsigned*)(part + 2 * 256 * 768);
    unsigned* rel   = flags + NBLK * FPAD;             // barriers * 16 lines

    fused_k<<<NBLK, NT, 0, stream>>>(
        feat, mask, aggW, aggB, attnW, updW, updB,
        WtH, part, flags, rel, (float*)d_out);
}